// Round 8
// baseline (169.508 us; speedup 1.0000x reference)
//
#include <hip/hip_runtime.h>

// Problem constants (from reference): B=4096, N_ELEM=2048, N_NODES=1024, E2=4096
#define B_SAMPLES 4096
#define N_ELEM    2048
#define N_NODES   1024
#define E2        4096
#define BLOCK     512                    // 8 waves/block; LDS caps 4 blocks/CU
#define SLOTS     32                     // max entries/node (Poisson mean 4)
#define S         4                      // samples per main block
#define MAIN_BLOCKS (B_SAMPLES / S)      // 1024

// Workspace layout (bytes):
//   [0, 4K)        : cnt[N_NODES]           (int)
//   [4K, 4K+512K)  : ell[SLOTS][N_NODES]    (float4 {wx, wy, bitcast(eid), pad})
#define WS_CNT_OFF   0
#define WS_ELL_OFF   4096

// ---------------------------------------------------------------------------
// Zero the per-node counters (ELL needs no zeroing: exact guards in main mean
// rows >= cnt[nid] are never read).
// ---------------------------------------------------------------------------
__global__ __launch_bounds__(N_NODES) void neq_zero_cnt(int* __restrict__ cnt)
{
    cnt[threadIdx.x] = 0;
}

// ---------------------------------------------------------------------------
// Build transposed-ELL via global atomics (order-independent sum).
// ---------------------------------------------------------------------------
__global__ __launch_bounds__(256) void neq_build_kernel(
    const float* __restrict__ vecs, const int* __restrict__ node_ids,
    const int* __restrict__ elem_ids, int* __restrict__ cnt,
    float4* __restrict__ ell)
{
    const int j = blockIdx.x * 256 + threadIdx.x;        // 0 .. E2-1
    int nid = node_ids[j];
    int eid = elem_ids[j];
    float2 v = ((const float2*)vecs)[j];
    int slot = atomicAdd(&cnt[nid], 1);                  // device-scope
    if (slot < SLOTS) {
        ell[slot * N_NODES + nid] = make_float4(v.x, v.y, __int_as_float(eid), 0.f);
    }
}

// ---------------------------------------------------------------------------
// Main: 512 threads, one block per S=4 samples, thread t owns nodes 2t,2t+1.
// axial stored as 4 per-sample LDS planes so phase-1 uses float4 global loads
// AND conflict-free ds_write_b128. q issued right after the barrier so its
// HBM stream overlaps the gather loop; r loaded in phase 3.
// ---------------------------------------------------------------------------
__global__ __launch_bounds__(BLOCK) void neq_main_kernel(
    const float* __restrict__ EA, const float* __restrict__ e,
    const float* __restrict__ q,  const float* __restrict__ r,
    const int* __restrict__ cnt, const float4* __restrict__ ell,
    float* __restrict__ out)
{
    __shared__ float axial[S * N_ELEM];  // 32 KiB: plane s at [s*2048 .. )
    __shared__ float red[BLOCK / 64];

    const int b0 = blockIdx.x * S;
    const int t = threadIdx.x;

    // ---- phase 1: axial planes, all-float4 (8 dwordx4 loads, b128 writes) ----
#pragma unroll
    for (int s = 0; s < S; ++s) {
        const float4* EA4 = (const float4*)(EA + (size_t)(b0 + s) * N_ELEM);
        const float4* e4  = (const float4*)(e  + (size_t)(b0 + s) * N_ELEM);
        float4 a = EA4[t];
        float4 m = e4[t];
        ((float4*)(axial + s * N_ELEM))[t] =
            make_float4(a.x * m.x, a.y * m.y, a.z * m.z, a.w * m.w);
    }

    int2 cc = ((const int2*)cnt)[t];                     // nodes 2t, 2t+1
    int c0 = min(cc.x, SLOTS);
    int c1 = min(cc.y, SLOTS);
    int kmax = max(c0, c1);
    __syncthreads();

    // ---- issue q stream now: overlaps HBM with the gather loop ----
    float4 qv[S];
#pragma unroll
    for (int s = 0; s < S; ++s)
        qv[s] = ((const float4*)(q + (size_t)(b0 + s) * N_NODES * 2))[t];

    // ---- phase 2: gather, exact per-node guards (padding never read) ----
    float accx[2][S] = {};
    float accy[2][S] = {};
    for (int k = 0; k < kmax; ++k) {
        const float4* row = ell + k * N_NODES + 2 * t;
#pragma unroll
        for (int i = 0; i < 2; ++i) {
            int ci = (i == 0) ? c0 : c1;
            if (k < ci) {
                float4 w = row[i];                       // coalesced 16B
                int eid = __float_as_int(w.z);
#pragma unroll
                for (int s = 0; s < S; ++s) {
                    float ax = axial[s * N_ELEM + eid];  // ds_read_b32
                    accx[i][s] += ax * w.x;
                    accy[i][s] += ax * w.y;
                }
            }
        }
    }

    // ---- phase 3: r loads, residual & sum of squares ----
    float acc = 0.f;
#pragma unroll
    for (int s = 0; s < S; ++s) {
        float4 rv = ((const float4*)(r + (size_t)(b0 + s) * N_NODES * 2))[t];
        float x0 = accx[0][s] - qv[s].x - rv.x;          // node 2t   (x)
        float y0 = accy[0][s] - qv[s].y - rv.y;          // node 2t   (y)
        float x1 = accx[1][s] - qv[s].z - rv.z;          // node 2t+1 (x)
        float y1 = accy[1][s] - qv[s].w - rv.w;          // node 2t+1 (y)
        acc += x0 * x0 + y0 * y0 + x1 * x1 + y1 * y1;
    }

    // ---- wave + block reduce, one global atomic per block ----
#pragma unroll
    for (int off = 32; off > 0; off >>= 1)
        acc += __shfl_down(acc, off, 64);
    if ((t & 63) == 0) red[t >> 6] = acc;
    __syncthreads();
    if (t == 0) {
        float s = 0.f;
#pragma unroll
        for (int w = 0; w < BLOCK / 64; ++w) s += red[w];
        const float inv_n = 1.0f / (float)((size_t)B_SAMPLES * N_NODES * 2);
        atomicAdd(out, s * inv_n);
    }
}

extern "C" void kernel_launch(void* const* d_in, const int* in_sizes, int n_in,
                              void* d_out, int out_size, void* d_ws, size_t ws_size,
                              hipStream_t stream) {
    const float* EA       = (const float*)d_in[0];
    const float* e        = (const float*)d_in[1];
    const float* q        = (const float*)d_in[2];
    const float* r        = (const float*)d_in[3];
    const float* vecs     = (const float*)d_in[4];
    const int*   node_ids = (const int*)d_in[5];
    const int*   elem_ids = (const int*)d_in[6];

    char* ws = (char*)d_ws;
    int*    cnt = (int*)(ws + WS_CNT_OFF);
    float4* ell = (float4*)(ws + WS_ELL_OFF);

    hipMemsetAsync(d_out, 0, sizeof(float), stream);     // accumulator for fused reduce

    neq_zero_cnt<<<1, N_NODES, 0, stream>>>(cnt);
    neq_build_kernel<<<E2 / 256, 256, 0, stream>>>(
        vecs, node_ids, elem_ids, cnt, ell);
    neq_main_kernel<<<MAIN_BLOCKS, BLOCK, 0, stream>>>(
        EA, e, q, r, cnt, ell, (float*)d_out);
}